// Round 1
// 2165.955 us; speedup vs baseline: 1.0315x; 1.0315x over previous
//
#include <hip/hip_runtime.h>
#include <stdint.h>

typedef __bf16 bf16;
typedef __attribute__((ext_vector_type(8))) __bf16 bf16x8;
typedef __attribute__((ext_vector_type(4))) __bf16 bf16x4;
typedef __attribute__((ext_vector_type(4))) float f32x4;

__device__ __forceinline__ void async16(bf16* lds, const bf16* g) {
  __builtin_amdgcn_global_load_lds(
      (const __attribute__((address_space(1))) void*)g,
      (__attribute__((address_space(3))) void*)lds, 16, 0, 0);
}

// ---------------- f32 -> bf16 elementwise convert (n multiple of 4) ----------
__global__ __launch_bounds__(256) void cvt_kernel(
    const float* __restrict__ in, bf16* __restrict__ out, int n4)
{
  int i = blockIdx.x * 256 + threadIdx.x;
  const int stride = gridDim.x * 256;
  for (; i < n4; i += stride) {
    const float4 v = ((const float4*)in)[i];
    bf16x4 o;
    o[0] = (bf16)v.x; o[1] = (bf16)v.y; o[2] = (bf16)v.z; o[3] = (bf16)v.w;
    ((bf16x4*)out)[i] = o;
  }
}

// ---------------- embedding: x = emb[ids]*sqrt(512) + pe (all f32) ----------
__global__ __launch_bounds__(256) void embed_kernel(
    const int* __restrict__ ids, const float* __restrict__ emb,
    const float* __restrict__ pe, float* __restrict__ x)
{
  const int tkn = blockIdx.x;          // 0..4095
  const int s = tkn & 1023;
  const int t = threadIdx.x;
  const int id = ids[tkn];
  const float* er = emb + (size_t)id * 512;
  const float* pr = pe + (size_t)s * 512;
  const float SQ = 22.627416997969522f;  // sqrt(512)
  x[(size_t)tkn*512 + t]       = er[t]     * SQ + pr[t];
  x[(size_t)tkn*512 + 256 + t] = er[256+t] * SQ + pr[256+t];
}

// ---------------- layernorm: f32 in, bf16 out ------------------------------
__global__ __launch_bounds__(256) void ln_kernel(
    const float* __restrict__ x, const float* __restrict__ gam,
    const float* __restrict__ bet, bf16* __restrict__ out)
{
  const int row = blockIdx.x, t = threadIdx.x;
  float a = x[(size_t)row*512 + t];
  float c = x[(size_t)row*512 + 256 + t];
  float s = a + c, ss = a*a + c*c;
  #pragma unroll
  for (int o = 1; o < 64; o <<= 1) {
    s  += __shfl_xor(s, o, 64);
    ss += __shfl_xor(ss, o, 64);
  }
  __shared__ float red[8];
  const int wid = t >> 6, lid = t & 63;
  if (lid == 0) { red[wid] = s; red[4+wid] = ss; }
  __syncthreads();
  const float S  = red[0]+red[1]+red[2]+red[3];
  const float SS = red[4]+red[5]+red[6]+red[7];
  const float mean = S * (1.0f/512.0f);
  const float var  = SS * (1.0f/512.0f) - mean*mean;
  const float rs = rsqrtf(var + 1e-5f);
  out[(size_t)row*512 + t]       = (bf16)((a-mean)*rs*gam[t]     + bet[t]);
  out[(size_t)row*512 + 256 + t] = (bf16)((c-mean)*rs*gam[256+t] + bet[256+t]);
}

// ------------- f32 transpose+cvt: in[R][C] f32 -> out[C][R] bf16 ------------
__global__ __launch_bounds__(256) void transpose_cvt(
    const float* __restrict__ in, bf16* __restrict__ out, int R, int C)
{
  __shared__ float tile[32][33];
  const int c0 = blockIdx.x * 32, r0 = blockIdx.y * 32;
  const int tx = threadIdx.x & 31, ty = threadIdx.x >> 5;   // 32 x 8
  #pragma unroll
  for (int i = 0; i < 32; i += 8)
    tile[ty+i][tx] = in[(size_t)(r0+ty+i)*C + c0+tx];
  __syncthreads();
  #pragma unroll
  for (int i = 0; i < 32; i += 8)
    out[(size_t)(c0+ty+i)*R + r0+tx] = (bf16)tile[tx][ty+i];
}

// ---------------- vT[bh][d][s] from v-part of qkv (row stride 1536) ----------
__global__ __launch_bounds__(256) void build_vT(
    const bf16* __restrict__ qkv, bf16* __restrict__ vT)
{
  __shared__ bf16 tl[64][65];
  const int bh = blockIdx.y, b = bh >> 3, h = bh & 7;
  const int s0 = blockIdx.x * 64;
  const int t = threadIdx.x;
  #pragma unroll
  for (int rr = 0; rr < 16; rr++) {
    int idx = t + rr*256;
    int sl = idx >> 6, d = idx & 63;
    tl[sl][d] = qkv[(size_t)(b*1024 + s0 + sl)*1536 + 1024 + h*64 + d];
  }
  __syncthreads();
  #pragma unroll
  for (int rr = 0; rr < 16; rr++) {
    int idx = t + rr*256;
    int d = idx >> 6, sl = idx & 63;
    vT[((size_t)bh*64 + d)*1024 + s0 + sl] = tl[sl][d];
  }
}

// ---------------- flash attention: one wave = 16 queries of one (b,h) --------
__global__ __launch_bounds__(256) void attn_kernel(
    const bf16* __restrict__ qkv, const bf16* __restrict__ vT,
    bf16* __restrict__ ctx)
{
  const int bh = blockIdx.y, b = bh >> 3, h = bh & 7;
  const int lane = threadIdx.x & 63, wave = threadIdx.x >> 6;
  const int q0 = blockIdx.x * 64 + wave * 16;
  const int qi = lane & 15, g = lane >> 4;
  const int qg = q0 + qi;                 // this lane's query (col in C layout)
  const f32x4 zero4 = {0.f, 0.f, 0.f, 0.f};

  const size_t qrow = (size_t)(b*1024 + qg) * 1536 + h*64;
  const bf16x8 qf0 = *(const bf16x8*)(qkv + qrow + g*8);        // B-frag dh 0..31
  const bf16x8 qf1 = *(const bf16x8*)(qkv + qrow + 32 + g*8);   // B-frag dh 32..63
  const bf16* vbase = vT + (size_t)bh * 64 * 1024;

  f32x4 O[4]; O[0]=zero4; O[1]=zero4; O[2]=zero4; O[3]=zero4;   // col=q, row=dim
  float m_run = -1e30f, l_run = 0.f;

  const int ktiles = (q0 + 15) / 32 + 1;
  for (int kt = 0; kt < ktiles; kt++) {
    const int k0 = kt * 32;
    const size_t krow0 = (size_t)(b*1024 + k0 + qi) * 1536 + 512 + h*64;
    const size_t krow1 = krow0 + (size_t)16 * 1536;
    bf16x8 ka00 = *(const bf16x8*)(qkv + krow0 + g*8);
    bf16x8 ka01 = *(const bf16x8*)(qkv + krow0 + 32 + g*8);
    bf16x8 ka10 = *(const bf16x8*)(qkv + krow1 + g*8);
    bf16x8 ka11 = *(const bf16x8*)(qkv + krow1 + 32 + g*8);
    // St[key][query], keys k0..k0+15 (s0) and k0+16..k0+31 (s1)
    f32x4 s0 = __builtin_amdgcn_mfma_f32_16x16x32_bf16(ka00, qf0, zero4, 0,0,0);
    s0 = __builtin_amdgcn_mfma_f32_16x16x32_bf16(ka01, qf1, s0, 0,0,0);
    f32x4 s1 = __builtin_amdgcn_mfma_f32_16x16x32_bf16(ka10, qf0, zero4, 0,0,0);
    s1 = __builtin_amdgcn_mfma_f32_16x16x32_bf16(ka11, qf1, s1, 0,0,0);

    float p0[4], p1[4];
    float mt = -1e30f;
    #pragma unroll
    for (int r = 0; r < 4; r++) {
      const int key0 = k0 + g*4 + r;
      const int key1 = key0 + 16;
      float a = s0[r] * 0.125f; if (key0 > qg) a = -1e30f;   // causal mask
      float c = s1[r] * 0.125f; if (key1 > qg) c = -1e30f;
      p0[r] = a; p1[r] = c;
      mt = fmaxf(mt, fmaxf(a, c));
    }
    // row(=query) reduction: lanes {qi, 16+qi, 32+qi, 48+qi}
    mt = fmaxf(mt, __shfl_xor(mt, 16, 64));
    mt = fmaxf(mt, __shfl_xor(mt, 32, 64));
    const float m_new = fmaxf(m_run, mt);
    const float alpha = __expf(m_run - m_new);
    float lsum = 0.f;
    #pragma unroll
    for (int r = 0; r < 4; r++) {
      p0[r] = __expf(p0[r] - m_new);
      p1[r] = __expf(p1[r] - m_new);
      lsum += p0[r] + p1[r];
    }
    lsum += __shfl_xor(lsum, 16, 64);
    lsum += __shfl_xor(lsum, 32, 64);
    l_run = l_run * alpha + lsum;
    m_run = m_new;
    #pragma unroll
    for (int ds = 0; ds < 4; ds++) O[ds] *= alpha;

    // P^T -> B-operand frag. Dest lane (qi,g) needs P^T[key=g*8+j][qi].
    // Source lane for key kk: g' = ((kk&15)>>2); value is p0 if kk<16 else p1.
    // Same src lane index works for both halves; select by dest's g&2.
    bf16x8 pf;
    #pragma unroll
    for (int j = 0; j < 8; j++) {
      const int src = ((2*g + (j >> 2)) & 3) * 16 + qi;
      const float v0 = __shfl(p0[j & 3], src, 64);
      const float v1 = __shfl(p1[j & 3], src, 64);
      pf[j] = (bf16)((g & 2) ? v1 : v0);
    }
    #pragma unroll
    for (int ds = 0; ds < 4; ds++) {
      const bf16x8 vf = *(const bf16x8*)(vbase + (size_t)(ds*16 + qi)*1024 + k0 + g*8);
      O[ds] = __builtin_amdgcn_mfma_f32_16x16x32_bf16(vf, pf, O[ds], 0,0,0);
    }
  }
  const float inv_l = 1.0f / l_run;
  #pragma unroll
  for (int ds = 0; ds < 4; ds++)
    #pragma unroll
    for (int r = 0; r < 4; r++)
      ctx[(size_t)(b*1024 + qg)*512 + h*64 + ds*16 + g*4 + r] = (bf16)(O[ds][r] * inv_l);
}

// ---------------- canonical B^T GEMM: C[M,N] = A[M,K] @ Bt[N,K]^T ------------
// 128x128 tile, BK=32, 4 waves (2x2) x (4x4 of 16x16x32 mfma).
// Double-buffered LDS (T3 minimum 2-phase): stage tile t+1 right after the
// barrier, BEFORE computing tile t -> global->LDS latency hides under
// ds_read+MFMA, and barrier count halves (1/K-step instead of 2).
#define EP_STORE 0   // C (bf16), no bias
#define EP_RESID 1   // F[m*512+n] += v + bias[n]   (f32 residual stream)
#define EP_GELU  2   // C (bf16) = gelu(v + bias[n])
#define EP_LOGIT 3   // F[m*ldc+n] = v              (f32 output, N-guarded)

template<int EP, bool GUARDN>
__global__ __launch_bounds__(256) void gemm_bt(
    const bf16* __restrict__ A, int lda,
    const bf16* __restrict__ Bt,          // [N][K] row-major
    bf16* __restrict__ C, int ldc,
    float* __restrict__ F,
    const float* __restrict__ bias,
    int N, int K)
{
  __shared__ bf16 As[2*128*32];           // 2 x 8 KB double buffer
  __shared__ bf16 Bs[2*128*32];
  const int tid = threadIdx.x;
  const int lane = tid & 63;
  const int wr = tid >> 7, wc = (tid >> 6) & 1;
  const int m0 = blockIdx.x * 128, n0 = blockIdx.y * 128;
  const int qi = lane & 15, g = lane >> 4;
  const int rs = tid >> 2, kb = (tid & 3) * 8;      // staging row / k-offset
  const bf16* gA0 = A + (size_t)(m0 + rs) * lda + kb;
  const bf16* gA1 = A + (size_t)(m0 + 64 + rs) * lda + kb;
  int nr0 = n0 + rs, nr1 = n0 + 64 + rs;
  if (GUARDN) { if (nr0 > N-1) nr0 = N-1; if (nr1 > N-1) nr1 = N-1; }
  const bf16* gB0 = Bt + (size_t)nr0 * K + kb;
  const bf16* gB1 = Bt + (size_t)nr1 * K + kb;
  bf16* ldsA = As + (tid & 192) * 8;                // wave-uniform LDS base
  bf16* ldsB = Bs + (tid & 192) * 8;

  const f32x4 zero4 = {0.f, 0.f, 0.f, 0.f};
  f32x4 acc[4][4];
  #pragma unroll
  for (int i = 0; i < 4; i++)
    #pragma unroll
    for (int j = 0; j < 4; j++) acc[i][j] = zero4;

  // prologue: stage K-tile 0 into buffer 0
  async16(ldsA,        gA0);
  async16(ldsA + 2048, gA1);
  async16(ldsB,        gB0);
  async16(ldsB + 2048, gB1);

  const int nt = K >> 5;
  int cur = 0;
  for (int t = 0; t < nt; t++) {
    __syncthreads();    // compiler drains vmcnt(0): tile t is in LDS;
                        // also fences last iter's reads of buf cur^1
    if (t + 1 < nt) {   // prefetch tile t+1 into the other buffer
      const int k = (t + 1) << 5;
      const int off = (cur ^ 1) * 4096;
      async16(ldsA + off,        gA0 + k);
      async16(ldsA + off + 2048, gA1 + k);
      async16(ldsB + off,        gB0 + k);
      async16(ldsB + off + 2048, gB1 + k);
    }
    const bf16* rA = As + cur * 4096;
    const bf16* rB = Bs + cur * 4096;
    bf16x8 af[4], bfr[4];
    #pragma unroll
    for (int i = 0; i < 4; i++)
      af[i] = *(const bf16x8*)(rA + (wr*64 + i*16 + qi)*32 + g*8);
    #pragma unroll
    for (int j = 0; j < 4; j++)
      bfr[j] = *(const bf16x8*)(rB + (wc*64 + j*16 + qi)*32 + g*8);
    #pragma unroll
    for (int i = 0; i < 4; i++)
      #pragma unroll
      for (int j = 0; j < 4; j++)
        acc[i][j] = __builtin_amdgcn_mfma_f32_16x16x32_bf16(af[i], bfr[j], acc[i][j], 0,0,0);
    cur ^= 1;
  }

  // epilogue: C layout col=lane&15, row=(lane>>4)*4+reg
  #pragma unroll
  for (int i = 0; i < 4; i++) {
    const int mb = m0 + wr*64 + i*16 + g*4;
    #pragma unroll
    for (int j = 0; j < 4; j++) {
      const int n = n0 + wc*64 + j*16 + qi;
      if (GUARDN && n >= N) continue;
      #pragma unroll
      for (int r = 0; r < 4; r++) {
        float v = acc[i][j][r];
        if (EP == EP_RESID) {
          F[(size_t)(mb + r)*512 + n] += v + bias[n];
        } else if (EP == EP_GELU) {
          v += bias[n];
          v = 0.5f * v * (1.0f + erff(v * 0.70710678118654752f));
          C[(size_t)(mb + r)*ldc + n] = (bf16)v;
        } else if (EP == EP_LOGIT) {
          F[(size_t)(mb + r)*ldc + n] = v;
        } else {
          C[(size_t)(mb + r)*ldc + n] = (bf16)v;
        }
      }
    }
  }
}

extern "C" void kernel_launch(void* const* d_in, const int* in_sizes, int n_in,
                              void* d_out, int out_size, void* d_ws, size_t ws_size,
                              hipStream_t stream) {
  const int*   ids  = (const int*)  d_in[0];
  const float* emb  = (const float*)d_in[1];
  const float* pe   = (const float*)d_in[2];
  const float* wq   = (const float*)d_in[3];
  const float* wk   = (const float*)d_in[4];
  const float* wv   = (const float*)d_in[5];
  const float* wo   = (const float*)d_in[6];
  const float* wo_b = (const float*)d_in[7];
  const float* w1   = (const float*)d_in[8];
  const float* b1   = (const float*)d_in[9];
  const float* w2   = (const float*)d_in[10];
  const float* b2   = (const float*)d_in[11];
  const float* ln1g = (const float*)d_in[12];
  const float* ln1b = (const float*)d_in[13];
  const float* ln2g = (const float*)d_in[14];
  const float* ln2b = (const float*)d_in[15];
  const float* lnfg = (const float*)d_in[16];
  const float* lnfb = (const float*)d_in[17];

  // workspace carving (~90 MB); ff1 aliases [qkv|vT] (disjoint lifetimes)
  char* p = (char*)d_ws;
  float* x    = (float*)p;  p += (size_t)4096*512*4;      // residual stream f32
  bf16* h     = (bf16*)p;   p += (size_t)4096*512*2;      // LN output
  bf16* region= (bf16*)p;   p += (size_t)4096*2048*2;     // qkv+vT / ff1
  bf16* qkv   = region;                                   // [4096][1536]
  bf16* vT    = region + (size_t)4096*1536;               // [32][64][1024]
  bf16* ff1   = region;                                   // [4096][2048]
  bf16* ctxb  = (bf16*)p;   p += (size_t)4096*512*2;
  bf16* wT    = (bf16*)p;   p += (size_t)1536*512*2;      // [wqT|wkT|wvT]
  bf16* woT   = (bf16*)p;   p += (size_t)512*512*2;
  bf16* w1T   = (bf16*)p;   p += (size_t)2048*512*2;
  bf16* w2T   = (bf16*)p;   p += (size_t)512*2048*2;
  bf16* embB  = (bf16*)p;   p += (size_t)50257*512*2;     // emb as bf16 [V][512]

  dim3 blk(256);
  transpose_cvt<<<dim3(16,16), blk, 0, stream>>>(wq, wT,             512, 512);
  transpose_cvt<<<dim3(16,16), blk, 0, stream>>>(wk, wT + 512*512,   512, 512);
  transpose_cvt<<<dim3(16,16), blk, 0, stream>>>(wv, wT + 2*512*512, 512, 512);
  transpose_cvt<<<dim3(16,16), blk, 0, stream>>>(wo, woT,            512, 512);
  transpose_cvt<<<dim3(64,16), blk, 0, stream>>>(w1, w1T,  512, 2048);
  transpose_cvt<<<dim3(16,64), blk, 0, stream>>>(w2, w2T, 2048,  512);
  cvt_kernel<<<2048, blk, 0, stream>>>(emb, embB, 50257*512/4);
  embed_kernel<<<4096, blk, 0, stream>>>(ids, emb, pe, x);

  for (int l = 0; l < 6; l++) {
    ln_kernel<<<4096, blk, 0, stream>>>(x, ln1g, ln1b, h);
    gemm_bt<EP_STORE,false><<<dim3(32,12), blk, 0, stream>>>(
        h, 512, wT, qkv, 1536, nullptr, nullptr, 1536, 512);
    build_vT<<<dim3(16,32), blk, 0, stream>>>(qkv, vT);
    attn_kernel<<<dim3(16,32), blk, 0, stream>>>(qkv, vT, ctxb);
    gemm_bt<EP_RESID,false><<<dim3(32,4), blk, 0, stream>>>(
        ctxb, 512, woT, nullptr, 0, x, wo_b, 512, 512);
    ln_kernel<<<4096, blk, 0, stream>>>(x, ln2g, ln2b, h);
    gemm_bt<EP_GELU,false><<<dim3(32,16), blk, 0, stream>>>(
        h, 512, w1T, ff1, 2048, nullptr, b1, 2048, 512);
    gemm_bt<EP_RESID,false><<<dim3(32,4), blk, 0, stream>>>(
        ff1, 2048, w2T, nullptr, 0, x, b2, 512, 2048);
  }
  ln_kernel<<<4096, blk, 0, stream>>>(x, lnfg, lnfb, h);
  gemm_bt<EP_LOGIT,true><<<dim3(32,393), blk, 0, stream>>>(
      h, 512, embB, nullptr, 50257, (float*)d_out, nullptr, 50257, 512);
}